// Round 14
// baseline (2418.233 us; speedup 1.0000x reference)
//
#include <hip/hip_runtime.h>
#include <hip/hip_bf16.h>
#include <math.h>

// Problem constants
constexpr int B = 16;
constexpr int S = 2048;
constexpr int H = 1024;
constexpr int E = 2048;

constexpr int ZA = 64;   // W_bil stage: 64 chunks of 16 rows
constexpr int ZB = 32;   // W_enc stage: 32 chunks of 32 rows

// DIAGNOSTIC ROUND: idempotent repeat loops to surface per-kernel cost in
// rocprof top-5 (harness fills at ~155us otherwise hide every kernel).
// Each rep redoes identical work and writes identical values -> deterministic.
constexpr int REP_A = 32;
constexpr int REP_B = 32;
constexpr int REP_S = 16;

// ---------------------------------------------------------------------------
// K_A (x32): qwp[z][b][h] = sum_{j<16} qp[b,z*16+j] * W_bil[z*16+j, h]
// ---------------------------------------------------------------------------
__global__ __launch_bounds__(256)
void k_A(const float* __restrict__ query,
         const float* __restrict__ W_q,
         const float* __restrict__ W_bil,
         float* __restrict__ qwp) {
    __shared__ float qpl[B][16];
    int z = blockIdx.y;
    int tid = threadIdx.x, wave = tid >> 6, lane = tid & 63;

    for (int rep = 0; rep < REP_A; ++rep) {
        // stage A: 16 qp rows for this chunk; wave w does rows w*4..w*4+3
        const float4* q4p = (const float4*)query;
        for (int rr = 0; rr < 4; ++rr) {
            int j = wave * 4 + rr;
            const float4* wrow = (const float4*)(W_q + (size_t)(z * 16 + j) * H);
            float acc[B];
            #pragma unroll
            for (int b = 0; b < B; ++b) acc[b] = 0.f;
            #pragma unroll
            for (int i = 0; i < 4; ++i) {
                float4 w4 = wrow[i * 64 + lane];
                #pragma unroll
                for (int b = 0; b < B; ++b) {
                    float4 qq = q4p[b * (H / 4) + i * 64 + lane];
                    acc[b] += w4.x * qq.x + w4.y * qq.y + w4.z * qq.z + w4.w * qq.w;
                }
            }
            #pragma unroll
            for (int off = 32; off; off >>= 1)
                #pragma unroll
                for (int b = 0; b < B; ++b)
                    acc[b] += __shfl_down(acc[b], off, 64);
            if (lane == 0) {
                #pragma unroll
                for (int b = 0; b < B; ++b) qpl[b][j] = acc[b];
            }
        }
        __syncthreads();

        // stage B: 16 fully-unrolled coalesced W_bil loads; 16 b-accums
        int h = blockIdx.x * 256 + tid;
        float acc[B];
        #pragma unroll
        for (int b = 0; b < B; ++b) acc[b] = 0.f;
        #pragma unroll
        for (int j = 0; j < 16; ++j) {
            float wv = W_bil[(size_t)(z * 16 + j) * H + h];
            #pragma unroll
            for (int b = 0; b < B; ++b) acc[b] += qpl[b][j] * wv;
        }
        #pragma unroll
        for (int b = 0; b < B; ++b)
            qwp[((size_t)z * B + b) * H + h] = acc[b];
        __syncthreads();   // protect qpl before next rep rewrites it
    }
}

// ---------------------------------------------------------------------------
// K_B (x32): up[z][b][e] = sum_{j<32} qw[b,z*32+j] * W_enc[z*32+j, e]
// ---------------------------------------------------------------------------
__global__ __launch_bounds__(256)
void k_B(const float* __restrict__ qwp,
         const float* __restrict__ W_enc,
         float* __restrict__ up) {
    __shared__ float qwl[B][32];
    int z = blockIdx.y;
    int tid = threadIdx.x;
    for (int rep = 0; rep < REP_B; ++rep) {
        for (int p = tid; p < B * 32; p += 256) {
            int b = p >> 5, j = p & 31;
            int h = z * 32 + j;
            float s = 0.f;
            #pragma unroll
            for (int zz = 0; zz < ZA; ++zz)
                s += qwp[((size_t)zz * B + b) * H + h];
            qwl[b][j] = s;
        }
        __syncthreads();
        int e = blockIdx.x * 256 + tid;
        float acc[B];
        #pragma unroll
        for (int b = 0; b < B; ++b) acc[b] = 0.f;
        #pragma unroll
        for (int j = 0; j < 32; ++j) {
            float wv = W_enc[(size_t)(z * 32 + j) * E + e];
            #pragma unroll
            for (int b = 0; b < B; ++b) acc[b] += qwl[b][j] * wv;
        }
        #pragma unroll
        for (int b = 0; b < B; ++b)
            up[((size_t)z * B + b) * E + e] = acc[b];
        __syncthreads();   // protect qwl before next rep
    }
}

// ---------------------------------------------------------------------------
// K_scores (x1, UNCHANGED): u-reduce prologue + 268 MB streaming dot.
// ---------------------------------------------------------------------------
__global__ __launch_bounds__(256)
void k_scores(const float* __restrict__ up,
              const float* __restrict__ value,
              const int* __restrict__ mask,
              float* __restrict__ scores) {
    __shared__ float su[E];        // 8 KB
    int b = blockIdx.y, tid = threadIdx.x;
    float4* su4 = (float4*)su;
    for (int c = tid; c < E / 4; c += 256) {
        float4 a = {0.f, 0.f, 0.f, 0.f};
        #pragma unroll
        for (int z = 0; z < ZB; ++z) {
            float4 p = ((const float4*)(up + ((size_t)z * B + b) * E))[c];
            a.x += p.x; a.y += p.y; a.z += p.z; a.w += p.w;
        }
        su4[c] = a;
    }
    __syncthreads();

    int w = tid >> 6, lane = tid & 63;
    float4 uu[8];
    #pragma unroll
    for (int i = 0; i < 8; ++i) uu[i] = su4[i * 64 + lane];
    int s0 = blockIdx.x * 16 + w * 4;
    #pragma unroll
    for (int r = 0; r < 4; r += 2) {
        int s = s0 + r;
        const float4* v0 = (const float4*)(value + ((size_t)(b * S + s)) * E);
        const float4* v1 = (const float4*)(value + ((size_t)(b * S + s + 1)) * E);
        float a0 = 0.f, a1 = 0.f;
        #pragma unroll
        for (int i = 0; i < 8; ++i) {
            float4 x0 = v0[i * 64 + lane];
            float4 x1 = v1[i * 64 + lane];
            a0 += x0.x * uu[i].x + x0.y * uu[i].y + x0.z * uu[i].z + x0.w * uu[i].w;
            a1 += x1.x * uu[i].x + x1.y * uu[i].y + x1.z * uu[i].z + x1.w * uu[i].w;
        }
        #pragma unroll
        for (int off = 32; off; off >>= 1) {
            a0 += __shfl_down(a0, off, 64);
            a1 += __shfl_down(a1, off, 64);
        }
        if (lane == 0) {
            scores[b * S + s]     = mask[b * S + s]     ? a0 : -INFINITY;
            scores[b * S + s + 1] = mask[b * S + s + 1] ? a1 : -INFINITY;
        }
    }
}

// ---------------------------------------------------------------------------
// K_smctx (x16): softmax + alphas + context, one block per batch.
// ---------------------------------------------------------------------------
__global__ void k_smctx(const float* __restrict__ scores,
                        const float* __restrict__ value,
                        float* __restrict__ alphas,
                        float* __restrict__ context) {
    __shared__ float sc[S];        // 8KB
    __shared__ float red[256];
    int b = blockIdx.x;
    int tid = threadIdx.x;
    for (int rep = 0; rep < REP_S; ++rep) {
        const float* srow = scores + b * S;
        float m = -INFINITY;
        for (int s = tid; s < S; s += 256) {
            float v = srow[s];
            sc[s] = v;
            m = fmaxf(m, v);
        }
        red[tid] = m;
        __syncthreads();
        for (int off = 128; off; off >>= 1) {
            if (tid < off) red[tid] = fmaxf(red[tid], red[tid + off]);
            __syncthreads();
        }
        m = red[0];
        __syncthreads();
        float l = 0.f;
        for (int s = tid; s < S; s += 256) {
            float p = __expf(sc[s] - m);
            sc[s] = p;
            l += p;
        }
        red[tid] = l;
        __syncthreads();
        for (int off = 128; off; off >>= 1) {
            if (tid < off) red[tid] += red[tid + off];
            __syncthreads();
        }
        float lsum = red[0];
        float inv = 1.f / lsum;
        float thresh = 1e-8f * lsum;
        for (int s = tid; s < S; s += 256)
            alphas[b * S + s] = sc[s] * inv;
        __syncthreads();
        float4 acc0 = {0.f, 0.f, 0.f, 0.f}, acc1 = {0.f, 0.f, 0.f, 0.f};
        for (int s = 0; s < S; ++s) {
            float p = sc[s];
            if (p > thresh) {
                const float4* vrow = (const float4*)(value + (size_t)(b * S + s) * E);
                float4 v0 = vrow[tid];
                float4 v1 = vrow[256 + tid];
                acc0.x += p * v0.x; acc0.y += p * v0.y; acc0.z += p * v0.z; acc0.w += p * v0.w;
                acc1.x += p * v1.x; acc1.y += p * v1.y; acc1.z += p * v1.z; acc1.w += p * v1.w;
            }
        }
        acc0.x *= inv; acc0.y *= inv; acc0.z *= inv; acc0.w *= inv;
        acc1.x *= inv; acc1.y *= inv; acc1.z *= inv; acc1.w *= inv;
        float4* ctx4 = (float4*)(context + (size_t)b * E);
        ctx4[tid] = acc0;
        ctx4[256 + tid] = acc1;
        __syncthreads();   // protect sc/red before next rep
    }
}

// ---------------------------------------------------------------------------
extern "C" void kernel_launch(void* const* d_in, const int* in_sizes, int n_in,
                              void* d_out, int out_size, void* d_ws, size_t ws_size,
                              hipStream_t stream) {
    const float* query = (const float*)d_in[0];   // [B,1,H]
    const float* value = (const float*)d_in[1];   // [B,S,E]
    const int*   mask  = (const int*)d_in[2];     // [B,1,S]
    const float* W_enc = (const float*)d_in[3];   // [H,E]
    const float* W_q   = (const float*)d_in[4];   // [H,H]
    const float* W_bil = (const float*)d_in[5];   // [H,H]

    float* out = (float*)d_out;
    float* context = out;          // [B,1,E]
    float* alphas  = out + B * E;  // [B,1,S]

    float* ws    = (float*)d_ws;
    float* sc_ws = ws;                              // B*S
    float* qwp   = sc_ws + B * S;                   // ZA*B*H (4 MB)
    float* up    = qwp + (size_t)ZA * B * H;        // ZB*B*E (4 MB)

    k_A<<<dim3(H / 256, ZA), 256, 0, stream>>>(query, W_q, W_bil, qwp);
    k_B<<<dim3(E / 256, ZB), 256, 0, stream>>>(qwp, W_enc, up);
    k_scores<<<dim3(S / 16, B), 256, 0, stream>>>(up, value, mask, sc_ws);
    k_smctx<<<dim3(B), 256, 0, stream>>>(sc_ws, value, alphas, context);
}

// Round 15
// 95.006 us; speedup vs baseline: 25.4535x; 25.4535x over previous
//
#include <hip/hip_runtime.h>
#include <hip/hip_bf16.h>
#include <math.h>

// Problem constants
constexpr int B = 16;
constexpr int S = 2048;
constexpr int H = 1024;
constexpr int E = 2048;

constexpr int ZA = 64;   // W_bil stage: 64 chunks of 16 rows
constexpr int ZB = 32;   // W_enc stage: 32 chunks of 32 rows

// ---------------------------------------------------------------------------
// K_A: qwp[z][b][h] = sum_{j<16} qp[b,z*16+j] * W_bil[z*16+j, h]
// qp rows computed INLINE (wave-per-row, 16 batch accums, butterfly reduce).
// grid (H/256=4, ZA=64) = 256 blocks x 256 thr.  ~22us with K_B (measured R14).
// ---------------------------------------------------------------------------
__global__ __launch_bounds__(256)
void k_A(const float* __restrict__ query,
         const float* __restrict__ W_q,
         const float* __restrict__ W_bil,
         float* __restrict__ qwp) {
    __shared__ float qpl[B][16];
    int z = blockIdx.y;
    int tid = threadIdx.x, wave = tid >> 6, lane = tid & 63;

    const float4* q4p = (const float4*)query;
    for (int rr = 0; rr < 4; ++rr) {
        int j = wave * 4 + rr;
        const float4* wrow = (const float4*)(W_q + (size_t)(z * 16 + j) * H);
        float acc[B];
        #pragma unroll
        for (int b = 0; b < B; ++b) acc[b] = 0.f;
        #pragma unroll
        for (int i = 0; i < 4; ++i) {
            float4 w4 = wrow[i * 64 + lane];
            #pragma unroll
            for (int b = 0; b < B; ++b) {
                float4 qq = q4p[b * (H / 4) + i * 64 + lane];
                acc[b] += w4.x * qq.x + w4.y * qq.y + w4.z * qq.z + w4.w * qq.w;
            }
        }
        #pragma unroll
        for (int off = 32; off; off >>= 1)
            #pragma unroll
            for (int b = 0; b < B; ++b)
                acc[b] += __shfl_down(acc[b], off, 64);
        if (lane == 0) {
            #pragma unroll
            for (int b = 0; b < B; ++b) qpl[b][j] = acc[b];
        }
    }
    __syncthreads();

    int h = blockIdx.x * 256 + tid;
    float acc[B];
    #pragma unroll
    for (int b = 0; b < B; ++b) acc[b] = 0.f;
    #pragma unroll
    for (int j = 0; j < 16; ++j) {
        float wv = W_bil[(size_t)(z * 16 + j) * H + h];
        #pragma unroll
        for (int b = 0; b < B; ++b) acc[b] += qpl[b][j] * wv;
    }
    #pragma unroll
    for (int b = 0; b < B; ++b)
        qwp[((size_t)z * B + b) * H + h] = acc[b];
}

// ---------------------------------------------------------------------------
// K_B: up[z][b][e] = sum_{j<32} qw[b,z*32+j] * W_enc[z*32+j, e]
// grid (E/256=8, ZB=32) = 256 blocks x 256 thr.
// ---------------------------------------------------------------------------
__global__ __launch_bounds__(256)
void k_B(const float* __restrict__ qwp,
         const float* __restrict__ W_enc,
         float* __restrict__ up) {
    __shared__ float qwl[B][32];
    int z = blockIdx.y;
    int tid = threadIdx.x;
    for (int p = tid; p < B * 32; p += 256) {
        int b = p >> 5, j = p & 31;
        int h = z * 32 + j;
        float s = 0.f;
        #pragma unroll
        for (int zz = 0; zz < ZA; ++zz)
            s += qwp[((size_t)zz * B + b) * H + h];
        qwl[b][j] = s;
    }
    __syncthreads();
    int e = blockIdx.x * 256 + tid;
    float acc[B];
    #pragma unroll
    for (int b = 0; b < B; ++b) acc[b] = 0.f;
    #pragma unroll
    for (int j = 0; j < 32; ++j) {
        float wv = W_enc[(size_t)(z * 32 + j) * E + e];
        #pragma unroll
        for (int b = 0; b < B; ++b) acc[b] += qwl[b][j] * wv;
    }
    #pragma unroll
    for (int b = 0; b < B; ++b)
        up[((size_t)z * B + b) * E + e] = acc[b];
}

// ---------------------------------------------------------------------------
// K_scores: u-reduce prologue (up L2-resident) + 268 MB streaming dot.
// grid (S/16=128, B) = 2048 blocks x 256 thr.  (proven)
// ---------------------------------------------------------------------------
__global__ __launch_bounds__(256)
void k_scores(const float* __restrict__ up,
              const float* __restrict__ value,
              const int* __restrict__ mask,
              float* __restrict__ scores) {
    __shared__ float su[E];        // 8 KB
    int b = blockIdx.y, tid = threadIdx.x;
    float4* su4 = (float4*)su;
    for (int c = tid; c < E / 4; c += 256) {
        float4 a = {0.f, 0.f, 0.f, 0.f};
        #pragma unroll
        for (int z = 0; z < ZB; ++z) {
            float4 p = ((const float4*)(up + ((size_t)z * B + b) * E))[c];
            a.x += p.x; a.y += p.y; a.z += p.z; a.w += p.w;
        }
        su4[c] = a;
    }
    __syncthreads();

    int w = tid >> 6, lane = tid & 63;
    float4 uu[8];
    #pragma unroll
    for (int i = 0; i < 8; ++i) uu[i] = su4[i * 64 + lane];
    int s0 = blockIdx.x * 16 + w * 4;
    #pragma unroll
    for (int r = 0; r < 4; r += 2) {
        int s = s0 + r;
        const float4* v0 = (const float4*)(value + ((size_t)(b * S + s)) * E);
        const float4* v1 = (const float4*)(value + ((size_t)(b * S + s + 1)) * E);
        float a0 = 0.f, a1 = 0.f;
        #pragma unroll
        for (int i = 0; i < 8; ++i) {
            float4 x0 = v0[i * 64 + lane];
            float4 x1 = v1[i * 64 + lane];
            a0 += x0.x * uu[i].x + x0.y * uu[i].y + x0.z * uu[i].z + x0.w * uu[i].w;
            a1 += x1.x * uu[i].x + x1.y * uu[i].y + x1.z * uu[i].z + x1.w * uu[i].w;
        }
        #pragma unroll
        for (int off = 32; off; off >>= 1) {
            a0 += __shfl_down(a0, off, 64);
            a1 += __shfl_down(a1, off, 64);
        }
        if (lane == 0) {
            scores[b * S + s]     = mask[b * S + s]     ? a0 : -INFINITY;
            scores[b * S + s + 1] = mask[b * S + s + 1] ? a1 : -INFINITY;
        }
    }
}

// ---------------------------------------------------------------------------
// K_smctx: softmax + alphas + COMPACTED context. One block per batch.
// R14 diagnosis: the old serial 2048-iter branchy context loop cost ~103us.
// Fix: deterministic stream compaction (wave shfl-scan + LDS wave offsets,
// stable ascending-s order, no atomics) -> loop over nsig (~1-5) rows only.
// Skip bound unchanged: dropped rows contribute <= 2048*1e-8*max|v| ~ 1e-4
// << 7.75e-2 threshold.
// ---------------------------------------------------------------------------
__global__ __launch_bounds__(256)
void k_smctx(const float* __restrict__ scores,
             const float* __restrict__ value,
             float* __restrict__ alphas,
             float* __restrict__ context) {
    __shared__ float sc[S];        // 8 KB  p-values
    __shared__ float red[256];
    __shared__ int   sig[S];       // 8 KB  compacted indices
    __shared__ int   wtot[4];
    __shared__ int   total;
    int b = blockIdx.x, tid = threadIdx.x;
    int lane = tid & 63, wv = tid >> 6;

    // pass 1: load scores, running max
    const float* srow = scores + b * S;
    float m = -INFINITY;
    for (int s = tid; s < S; s += 256) {
        float v = srow[s];
        sc[s] = v;
        m = fmaxf(m, v);
    }
    red[tid] = m;
    __syncthreads();
    for (int off = 128; off; off >>= 1) {
        if (tid < off) red[tid] = fmaxf(red[tid], red[tid + off]);
        __syncthreads();
    }
    m = red[0];
    __syncthreads();

    // pass 2: exp + sum
    float l = 0.f;
    for (int s = tid; s < S; s += 256) {
        float p = __expf(sc[s] - m);
        sc[s] = p;
        l += p;
    }
    red[tid] = l;
    __syncthreads();
    for (int off = 128; off; off >>= 1) {
        if (tid < off) red[tid] += red[tid + off];
        __syncthreads();
    }
    float lsum = red[0];
    float inv = 1.f / lsum;
    float thresh = 1e-8f * lsum;    // p > thresh  <=>  alpha > 1e-8

    // pass 3: alphas
    for (int s = tid; s < S; s += 256)
        alphas[b * S + s] = sc[s] * inv;

    // pass 4: deterministic compaction. Thread t owns s in [8t, 8t+8).
    int s8 = tid * 8;
    int cnt = 0;
    #pragma unroll
    for (int j = 0; j < 8; ++j) cnt += (sc[s8 + j] > thresh) ? 1 : 0;
    // wave-level inclusive scan of cnt
    int x = cnt;
    #pragma unroll
    for (int off = 1; off < 64; off <<= 1) {
        int y = __shfl_up(x, off, 64);
        if (lane >= off) x += y;
    }
    if (lane == 63) wtot[wv] = x;
    __syncthreads();
    int wbase = 0;
    #pragma unroll
    for (int i = 0; i < 4; ++i) wbase += (i < wv) ? wtot[i] : 0;
    int k = wbase + x - cnt;       // exclusive prefix, stable order
    #pragma unroll
    for (int j = 0; j < 8; ++j) {
        if (sc[s8 + j] > thresh) sig[k++] = s8 + j;
    }
    if (tid == 255) total = wbase + x;
    __syncthreads();
    int nsig = total;

    // pass 5: context over compacted rows only (branch-free, parallel loads)
    float4 acc0 = {0.f, 0.f, 0.f, 0.f}, acc1 = {0.f, 0.f, 0.f, 0.f};
    for (int i = 0; i < nsig; ++i) {
        int s = sig[i];
        float p = sc[s];
        const float4* vrow = (const float4*)(value + (size_t)(b * S + s) * E);
        float4 v0 = vrow[tid];
        float4 v1 = vrow[256 + tid];
        acc0.x += p * v0.x; acc0.y += p * v0.y; acc0.z += p * v0.z; acc0.w += p * v0.w;
        acc1.x += p * v1.x; acc1.y += p * v1.y; acc1.z += p * v1.z; acc1.w += p * v1.w;
    }
    acc0.x *= inv; acc0.y *= inv; acc0.z *= inv; acc0.w *= inv;
    acc1.x *= inv; acc1.y *= inv; acc1.z *= inv; acc1.w *= inv;
    float4* ctx4 = (float4*)(context + (size_t)b * E);
    ctx4[tid] = acc0;
    ctx4[256 + tid] = acc1;
}

// ---------------------------------------------------------------------------
extern "C" void kernel_launch(void* const* d_in, const int* in_sizes, int n_in,
                              void* d_out, int out_size, void* d_ws, size_t ws_size,
                              hipStream_t stream) {
    const float* query = (const float*)d_in[0];   // [B,1,H]
    const float* value = (const float*)d_in[1];   // [B,S,E]
    const int*   mask  = (const int*)d_in[2];     // [B,1,S]
    const float* W_enc = (const float*)d_in[3];   // [H,E]
    const float* W_q   = (const float*)d_in[4];   // [H,H]
    const float* W_bil = (const float*)d_in[5];   // [H,H]

    float* out = (float*)d_out;
    float* context = out;          // [B,1,E]
    float* alphas  = out + B * E;  // [B,1,S]

    float* ws    = (float*)d_ws;
    float* sc_ws = ws;                              // B*S
    float* qwp   = sc_ws + B * S;                   // ZA*B*H (4 MB)
    float* up    = qwp + (size_t)ZA * B * H;        // ZB*B*E (4 MB)

    // 4 nodes, all deterministic, no fences/atomics
    k_A<<<dim3(H / 256, ZA), 256, 0, stream>>>(query, W_q, W_bil, qwp);
    k_B<<<dim3(E / 256, ZB), 256, 0, stream>>>(qwp, W_enc, up);
    k_scores<<<dim3(S / 16, B), 256, 0, stream>>>(up, value, mask, sc_ws);
    k_smctx<<<dim3(B), 256, 0, stream>>>(sc_ws, value, alphas, context);
}

// Round 16
// 87.010 us; speedup vs baseline: 27.7926x; 1.0919x over previous
//
#include <hip/hip_runtime.h>
#include <hip/hip_bf16.h>
#include <math.h>

// Problem constants
constexpr int B = 16;
constexpr int S = 2048;
constexpr int H = 1024;
constexpr int E = 2048;

constexpr int ZA = 64;   // W_bil stage: 64 chunks of 16 rows
constexpr int ZB = 32;   // W_enc stage: 32 chunks of 32 rows

// ---------------------------------------------------------------------------
// K_A: qwp[z][b][h] = sum_{j<16} qp[b,z*16+j] * W_bil[z*16+j, h]
// qp rows computed INLINE (wave-per-row, 16 batch accums, butterfly reduce).
// grid (H/256=4, ZA=64) = 256 blocks x 256 thr.  ~22us with K_B (measured R14).
// ---------------------------------------------------------------------------
__global__ __launch_bounds__(256)
void k_A(const float* __restrict__ query,
         const float* __restrict__ W_q,
         const float* __restrict__ W_bil,
         float* __restrict__ qwp) {
    __shared__ float qpl[B][16];
    int z = blockIdx.y;
    int tid = threadIdx.x, wave = tid >> 6, lane = tid & 63;

    const float4* q4p = (const float4*)query;
    for (int rr = 0; rr < 4; ++rr) {
        int j = wave * 4 + rr;
        const float4* wrow = (const float4*)(W_q + (size_t)(z * 16 + j) * H);
        float acc[B];
        #pragma unroll
        for (int b = 0; b < B; ++b) acc[b] = 0.f;
        #pragma unroll
        for (int i = 0; i < 4; ++i) {
            float4 w4 = wrow[i * 64 + lane];
            #pragma unroll
            for (int b = 0; b < B; ++b) {
                float4 qq = q4p[b * (H / 4) + i * 64 + lane];
                acc[b] += w4.x * qq.x + w4.y * qq.y + w4.z * qq.z + w4.w * qq.w;
            }
        }
        #pragma unroll
        for (int off = 32; off; off >>= 1)
            #pragma unroll
            for (int b = 0; b < B; ++b)
                acc[b] += __shfl_down(acc[b], off, 64);
        if (lane == 0) {
            #pragma unroll
            for (int b = 0; b < B; ++b) qpl[b][j] = acc[b];
        }
    }
    __syncthreads();

    int h = blockIdx.x * 256 + tid;
    float acc[B];
    #pragma unroll
    for (int b = 0; b < B; ++b) acc[b] = 0.f;
    #pragma unroll
    for (int j = 0; j < 16; ++j) {
        float wv = W_bil[(size_t)(z * 16 + j) * H + h];
        #pragma unroll
        for (int b = 0; b < B; ++b) acc[b] += qpl[b][j] * wv;
    }
    #pragma unroll
    for (int b = 0; b < B; ++b)
        qwp[((size_t)z * B + b) * H + h] = acc[b];
}

// ---------------------------------------------------------------------------
// K_B: up[z][b][e] = sum_{j<32} qw[b,z*32+j] * W_enc[z*32+j, e]
// grid (E/256=8, ZB=32) = 256 blocks x 256 thr.
// ---------------------------------------------------------------------------
__global__ __launch_bounds__(256)
void k_B(const float* __restrict__ qwp,
         const float* __restrict__ W_enc,
         float* __restrict__ up) {
    __shared__ float qwl[B][32];
    int z = blockIdx.y;
    int tid = threadIdx.x;
    for (int p = tid; p < B * 32; p += 256) {
        int b = p >> 5, j = p & 31;
        int h = z * 32 + j;
        float s = 0.f;
        #pragma unroll
        for (int zz = 0; zz < ZA; ++zz)
            s += qwp[((size_t)zz * B + b) * H + h];
        qwl[b][j] = s;
    }
    __syncthreads();
    int e = blockIdx.x * 256 + tid;
    float acc[B];
    #pragma unroll
    for (int b = 0; b < B; ++b) acc[b] = 0.f;
    #pragma unroll
    for (int j = 0; j < 32; ++j) {
        float wv = W_enc[(size_t)(z * 32 + j) * E + e];
        #pragma unroll
        for (int b = 0; b < B; ++b) acc[b] += qwl[b][j] * wv;
    }
    #pragma unroll
    for (int b = 0; b < B; ++b)
        up[((size_t)z * B + b) * E + e] = acc[b];
}

// ---------------------------------------------------------------------------
// K_ured: u = sum_z up[z].  32 blocks x 256 thr, float4; up is L2-resident
// (4 MB). Removes the 512 MB aggregate L2 re-reduce from k_scores' prologue.
// ---------------------------------------------------------------------------
__global__ __launch_bounds__(256)
void k_ured(const float* __restrict__ up,
            float* __restrict__ u) {
    int idx = blockIdx.x * 256 + threadIdx.x;   // float4 index, B*E/4 = 8192
    float4 a = {0.f, 0.f, 0.f, 0.f};
    #pragma unroll
    for (int z = 0; z < ZB; ++z) {
        float4 p = ((const float4*)up)[(size_t)z * (B * E / 4) + idx];
        a.x += p.x; a.y += p.y; a.z += p.z; a.w += p.w;
    }
    ((float4*)u)[idx] = a;
}

// ---------------------------------------------------------------------------
// K_scores: load u[b] (8 KB, L2) into LDS + 268 MB streaming dot. (proven)
// grid (S/16=128, B) = 2048 blocks x 256 thr.
// ---------------------------------------------------------------------------
__global__ __launch_bounds__(256)
void k_scores(const float* __restrict__ u,
              const float* __restrict__ value,
              const int* __restrict__ mask,
              float* __restrict__ scores) {
    __shared__ float su[E];        // 8 KB
    int b = blockIdx.y, tid = threadIdx.x;
    float4* su4 = (float4*)su;
    const float4* ug = (const float4*)(u + (size_t)b * E);
    for (int c = tid; c < E / 4; c += 256) su4[c] = ug[c];
    __syncthreads();

    int w = tid >> 6, lane = tid & 63;
    float4 uu[8];
    #pragma unroll
    for (int i = 0; i < 8; ++i) uu[i] = su4[i * 64 + lane];
    int s0 = blockIdx.x * 16 + w * 4;
    #pragma unroll
    for (int r = 0; r < 4; r += 2) {
        int s = s0 + r;
        const float4* v0 = (const float4*)(value + ((size_t)(b * S + s)) * E);
        const float4* v1 = (const float4*)(value + ((size_t)(b * S + s + 1)) * E);
        float a0 = 0.f, a1 = 0.f;
        #pragma unroll
        for (int i = 0; i < 8; ++i) {
            float4 x0 = v0[i * 64 + lane];
            float4 x1 = v1[i * 64 + lane];
            a0 += x0.x * uu[i].x + x0.y * uu[i].y + x0.z * uu[i].z + x0.w * uu[i].w;
            a1 += x1.x * uu[i].x + x1.y * uu[i].y + x1.z * uu[i].z + x1.w * uu[i].w;
        }
        #pragma unroll
        for (int off = 32; off; off >>= 1) {
            a0 += __shfl_down(a0, off, 64);
            a1 += __shfl_down(a1, off, 64);
        }
        if (lane == 0) {
            scores[b * S + s]     = mask[b * S + s]     ? a0 : -INFINITY;
            scores[b * S + s + 1] = mask[b * S + s + 1] ? a1 : -INFINITY;
        }
    }
}

// ---------------------------------------------------------------------------
// K_smctx: softmax + alphas + COMPACTED context. One block per batch.
// (R15-proven: ~103us -> ~5-8us via deterministic stream compaction.)
// Skip bound: dropped rows contribute <= 2048*1e-8*max|v| ~ 1e-4 << 7.75e-2.
// ---------------------------------------------------------------------------
__global__ __launch_bounds__(256)
void k_smctx(const float* __restrict__ scores,
             const float* __restrict__ value,
             float* __restrict__ alphas,
             float* __restrict__ context) {
    __shared__ float sc[S];        // 8 KB  p-values
    __shared__ float red[256];
    __shared__ int   sig[S];       // 8 KB  compacted indices
    __shared__ int   wtot[4];
    __shared__ int   total;
    int b = blockIdx.x, tid = threadIdx.x;
    int lane = tid & 63, wv = tid >> 6;

    const float* srow = scores + b * S;
    float m = -INFINITY;
    for (int s = tid; s < S; s += 256) {
        float v = srow[s];
        sc[s] = v;
        m = fmaxf(m, v);
    }
    red[tid] = m;
    __syncthreads();
    for (int off = 128; off; off >>= 1) {
        if (tid < off) red[tid] = fmaxf(red[tid], red[tid + off]);
        __syncthreads();
    }
    m = red[0];
    __syncthreads();

    float l = 0.f;
    for (int s = tid; s < S; s += 256) {
        float p = __expf(sc[s] - m);
        sc[s] = p;
        l += p;
    }
    red[tid] = l;
    __syncthreads();
    for (int off = 128; off; off >>= 1) {
        if (tid < off) red[tid] += red[tid + off];
        __syncthreads();
    }
    float lsum = red[0];
    float inv = 1.f / lsum;
    float thresh = 1e-8f * lsum;    // p > thresh  <=>  alpha > 1e-8

    for (int s = tid; s < S; s += 256)
        alphas[b * S + s] = sc[s] * inv;

    // deterministic compaction; thread t owns s in [8t, 8t+8)
    int s8 = tid * 8;
    int cnt = 0;
    #pragma unroll
    for (int j = 0; j < 8; ++j) cnt += (sc[s8 + j] > thresh) ? 1 : 0;
    int x = cnt;
    #pragma unroll
    for (int off = 1; off < 64; off <<= 1) {
        int y = __shfl_up(x, off, 64);
        if (lane >= off) x += y;
    }
    if (lane == 63) wtot[wv] = x;
    __syncthreads();
    int wbase = 0;
    #pragma unroll
    for (int i = 0; i < 4; ++i) wbase += (i < wv) ? wtot[i] : 0;
    int k = wbase + x - cnt;       // stable exclusive prefix
    #pragma unroll
    for (int j = 0; j < 8; ++j) {
        if (sc[s8 + j] > thresh) sig[k++] = s8 + j;
    }
    if (tid == 255) total = wbase + x;
    __syncthreads();
    int nsig = total;

    float4 acc0 = {0.f, 0.f, 0.f, 0.f}, acc1 = {0.f, 0.f, 0.f, 0.f};
    for (int i = 0; i < nsig; ++i) {
        int s = sig[i];
        float p = sc[s];
        const float4* vrow = (const float4*)(value + (size_t)(b * S + s) * E);
        float4 v0 = vrow[tid];
        float4 v1 = vrow[256 + tid];
        acc0.x += p * v0.x; acc0.y += p * v0.y; acc0.z += p * v0.z; acc0.w += p * v0.w;
        acc1.x += p * v1.x; acc1.y += p * v1.y; acc1.z += p * v1.z; acc1.w += p * v1.w;
    }
    acc0.x *= inv; acc0.y *= inv; acc0.z *= inv; acc0.w *= inv;
    acc1.x *= inv; acc1.y *= inv; acc1.z *= inv; acc1.w *= inv;
    float4* ctx4 = (float4*)(context + (size_t)b * E);
    ctx4[tid] = acc0;
    ctx4[256 + tid] = acc1;
}

// ---------------------------------------------------------------------------
extern "C" void kernel_launch(void* const* d_in, const int* in_sizes, int n_in,
                              void* d_out, int out_size, void* d_ws, size_t ws_size,
                              hipStream_t stream) {
    const float* query = (const float*)d_in[0];   // [B,1,H]
    const float* value = (const float*)d_in[1];   // [B,S,E]
    const int*   mask  = (const int*)d_in[2];     // [B,1,S]
    const float* W_enc = (const float*)d_in[3];   // [H,E]
    const float* W_q   = (const float*)d_in[4];   // [H,H]
    const float* W_bil = (const float*)d_in[5];   // [H,H]

    float* out = (float*)d_out;
    float* context = out;          // [B,1,E]
    float* alphas  = out + B * E;  // [B,1,S]

    float* ws    = (float*)d_ws;
    float* sc_ws = ws;                              // B*S
    float* u     = sc_ws + B * S;                   // B*E
    float* qwp   = u + B * E;                       // ZA*B*H (4 MB)
    float* up    = qwp + (size_t)ZA * B * H;        // ZB*B*E (4 MB)

    // 5 nodes, all deterministic, no fences/atomics
    k_A<<<dim3(H / 256, ZA), 256, 0, stream>>>(query, W_q, W_bil, qwp);
    k_B<<<dim3(E / 256, ZB), 256, 0, stream>>>(qwp, W_enc, up);
    k_ured<<<dim3(B * E / 1024), 256, 0, stream>>>(up, u);
    k_scores<<<dim3(S / 16, B), 256, 0, stream>>>(u, value, mask, sc_ws);
    k_smctx<<<dim3(B), 256, 0, stream>>>(sc_ws, value, alphas, context);
}